// Round 1
// baseline (108.848 us; speedup 1.0000x reference)
//
#include <hip/hip_runtime.h>
#include <cmath>

// Problem constants (from reference): B=4, T=1, DIN=4096, DOUT=11008, RANK=512
constexpr int DIN  = 4096;
constexpr int DOUT = 11008;
constexpr int RANK = 512;
constexpr int NB   = 4;

constexpr int NCHUNK = 256;          // d-chunks for lr partials
constexpr int DCH    = DIN / NCHUNK; // 16 d's per chunk

// ---------------------------------------------------------------------------
// Phase 1: partial[chunk][b][r] = sum_{d in chunk} xc[b][d] * V[d][r]
//   xc = x * (1 - mask),  mask = |x*scale| > th
// grid = NCHUNK blocks, 512 threads (one per r)
// ---------------------------------------------------------------------------
__global__ __launch_bounds__(512)
void lr_partial_kernel(const float* __restrict__ x,
                       const float* __restrict__ scale,
                       const float* __restrict__ thp,
                       const float* __restrict__ V,
                       float* __restrict__ partial)
{
    __shared__ float xc[NB * DCH];
    const int chunk = blockIdx.x;
    const int t = threadIdx.x;
    const float th = thp[0];
    if (t < NB * DCH) {
        const int b = t / DCH, dd = t % DCH;
        const int d = chunk * DCH + dd;
        const float xv = x[b * DIN + d];
        // complement path: keep value where mask == 0
        xc[t] = (fabsf(xv * scale[d]) > th) ? 0.f : xv;
    }
    __syncthreads();
    const int r = t; // 0..511
    float a0 = 0.f, a1 = 0.f, a2 = 0.f, a3 = 0.f;
    #pragma unroll
    for (int dd = 0; dd < DCH; ++dd) {
        const float v = V[(size_t)(chunk * DCH + dd) * RANK + r];
        a0 = fmaf(xc[0 * DCH + dd], v, a0);
        a1 = fmaf(xc[1 * DCH + dd], v, a1);
        a2 = fmaf(xc[2 * DCH + dd], v, a2);
        a3 = fmaf(xc[3 * DCH + dd], v, a3);
    }
    float* p = partial + (size_t)chunk * (NB * RANK) + r;
    p[0 * RANK] = a0;
    p[1 * RANK] = a1;
    p[2 * RANK] = a2;
    p[3 * RANK] = a3;
}

// ---------------------------------------------------------------------------
// Phase 2: lr[b][r] = S[r] * sum_chunk partial[chunk][b][r]
// grid = (NB*RANK)/64 blocks x 64 threads — deterministic reduction
// ---------------------------------------------------------------------------
__global__ __launch_bounds__(64)
void lr_reduce_kernel(const float* __restrict__ partial,
                      const float* __restrict__ S,
                      float* __restrict__ lr)
{
    const int idx = blockIdx.x * 64 + threadIdx.x; // 0..NB*RANK-1
    const int r = idx & (RANK - 1);
    float s = 0.f;
    #pragma unroll 8
    for (int c = 0; c < NCHUNK; ++c)
        s += partial[(size_t)c * (NB * RANK) + idx];
    lr[idx] = s * S[r];
}

// ---------------------------------------------------------------------------
// Phase 3 (main): out[b][o] = bias[o] + sum_d xs[b][d]*W[o][d]
//                            + sum_r lr[b][r]*U[o][r]
// One wave handles 2 consecutive o's for all 4 batches; block = 4 waves = 8 o.
// xs (masked input) and lr staged in dynamic LDS (72 KB).
// ---------------------------------------------------------------------------
constexpr int OTILE = 8; // o's per block

__global__ __launch_bounds__(256)
void rsparse_main_kernel(const float* __restrict__ x,
                         const float* __restrict__ scale,
                         const float* __restrict__ thp,
                         const float* __restrict__ W,
                         const float* __restrict__ bias,
                         const float* __restrict__ U,
                         const float* __restrict__ lr,
                         float* __restrict__ out)
{
    extern __shared__ float smem[];
    float* sxs = smem;            // [NB][DIN]  masked input
    float* slr = smem + NB * DIN; // [NB][RANK]
    const int tid = threadIdx.x;
    const float th = thp[0];

    for (int i = tid; i < NB * DIN; i += 256) {
        const int d = i & (DIN - 1);
        const float xv = x[i];
        sxs[i] = (fabsf(xv * scale[d]) > th) ? xv : 0.f;
    }
    for (int i = tid; i < NB * RANK; i += 256)
        slr[i] = lr[i];
    __syncthreads();

    const int wave = tid >> 6, lane = tid & 63;
    const int o0 = blockIdx.x * OTILE + wave * 2;
    const int o1 = o0 + 1;

    const float4* __restrict__ W0 = (const float4*)(W + (size_t)o0 * DIN);
    const float4* __restrict__ W1 = (const float4*)(W + (size_t)o1 * DIN);
    const float4* XS = (const float4*)sxs; // [NB][1024]
    const float4* LR = (const float4*)slr; // [NB][128]

    float acc0[NB] = {0.f, 0.f, 0.f, 0.f};
    float acc1[NB] = {0.f, 0.f, 0.f, 0.f};

    #pragma unroll 4
    for (int k = 0; k < 16; ++k) {
        const int c = (k << 6) + lane;
        const float4 w0 = W0[c];
        const float4 w1 = W1[c];
        #pragma unroll
        for (int b = 0; b < NB; ++b) {
            const float4 xv = XS[b * 1024 + c];
            acc0[b] = fmaf(w0.x, xv.x, acc0[b]);
            acc0[b] = fmaf(w0.y, xv.y, acc0[b]);
            acc0[b] = fmaf(w0.z, xv.z, acc0[b]);
            acc0[b] = fmaf(w0.w, xv.w, acc0[b]);
            acc1[b] = fmaf(w1.x, xv.x, acc1[b]);
            acc1[b] = fmaf(w1.y, xv.y, acc1[b]);
            acc1[b] = fmaf(w1.z, xv.z, acc1[b]);
            acc1[b] = fmaf(w1.w, xv.w, acc1[b]);
        }
    }

    const float4* __restrict__ U0 = (const float4*)(U + (size_t)o0 * RANK);
    const float4* __restrict__ U1 = (const float4*)(U + (size_t)o1 * RANK);
    #pragma unroll
    for (int j = 0; j < 2; ++j) {
        const int c = (j << 6) + lane;
        const float4 u0 = U0[c];
        const float4 u1 = U1[c];
        #pragma unroll
        for (int b = 0; b < NB; ++b) {
            const float4 lv = LR[b * 128 + c];
            acc0[b] = fmaf(u0.x, lv.x, acc0[b]);
            acc0[b] = fmaf(u0.y, lv.y, acc0[b]);
            acc0[b] = fmaf(u0.z, lv.z, acc0[b]);
            acc0[b] = fmaf(u0.w, lv.w, acc0[b]);
            acc1[b] = fmaf(u1.x, lv.x, acc1[b]);
            acc1[b] = fmaf(u1.y, lv.y, acc1[b]);
            acc1[b] = fmaf(u1.z, lv.z, acc1[b]);
            acc1[b] = fmaf(u1.w, lv.w, acc1[b]);
        }
    }

    // full-wave (64-lane) butterfly reduction
    #pragma unroll
    for (int b = 0; b < NB; ++b) {
        #pragma unroll
        for (int m = 32; m >= 1; m >>= 1) {
            acc0[b] += __shfl_xor(acc0[b], m, 64);
            acc1[b] += __shfl_xor(acc1[b], m, 64);
        }
    }

    if (lane == 0) {
        const float bi0 = bias[o0], bi1 = bias[o1];
        #pragma unroll
        for (int b = 0; b < NB; ++b) {
            out[b * DOUT + o0] = acc0[b] + bi0;
            out[b * DOUT + o1] = acc1[b] + bi1;
        }
    }
}

// ---------------------------------------------------------------------------
extern "C" void kernel_launch(void* const* d_in, const int* in_sizes, int n_in,
                              void* d_out, int out_size, void* d_ws, size_t ws_size,
                              hipStream_t stream)
{
    const float* x     = (const float*)d_in[0]; // [4][1][4096]
    const float* W     = (const float*)d_in[1]; // [11008][4096]
    const float* bias  = (const float*)d_in[2]; // [11008]
    const float* U     = (const float*)d_in[3]; // [11008][512]
    const float* S     = (const float*)d_in[4]; // [512]
    const float* V     = (const float*)d_in[5]; // [4096][512]
    const float* scale = (const float*)d_in[6]; // [4096]
    const float* thp   = (const float*)d_in[7]; // [1]
    float* out = (float*)d_out;                 // [4][1][11008]

    float* partial = (float*)d_ws;                        // NCHUNK*NB*RANK f32 (2 MB)
    float* lr      = partial + (size_t)NCHUNK * NB * RANK; // NB*RANK f32

    lr_partial_kernel<<<NCHUNK, 512, 0, stream>>>(x, scale, thp, V, partial);
    lr_reduce_kernel<<<(NB * RANK) / 64, 64, 0, stream>>>(partial, S, lr);

    const size_t smem = (size_t)(NB * DIN + NB * RANK) * sizeof(float); // 72 KB
    rsparse_main_kernel<<<DOUT / OTILE, 256, smem, stream>>>(
        x, scale, thp, W, bias, U, lr, out);
}

// Round 2
// 63.186 us; speedup vs baseline: 1.7227x; 1.7227x over previous
//
#include <hip/hip_runtime.h>
#include <cmath>

// Problem constants: B=4, T=1, DIN=4096, DOUT=11008, RANK=512
constexpr int DIN  = 4096;
constexpr int DOUT = 11008;
constexpr int RANK = 512;
constexpr int NB   = 4;

constexpr int NCHUNK = 256;          // d-chunks for lr partials
constexpr int DCH    = DIN / NCHUNK; // 16 d's per chunk

// ---------------------------------------------------------------------------
// Prep: xs[b][d] = x * mask (sparse path input), stored to workspace
// ---------------------------------------------------------------------------
__global__ __launch_bounds__(256)
void prep_xs_kernel(const float* __restrict__ x,
                    const float* __restrict__ scale,
                    const float* __restrict__ thp,
                    float* __restrict__ xs)
{
    const int i = blockIdx.x * 256 + threadIdx.x; // 0..NB*DIN-1
    const float th = thp[0];
    const int d = i & (DIN - 1);
    const float xv = x[i];
    xs[i] = (fabsf(xv * scale[d]) > th) ? xv : 0.f;
}

// ---------------------------------------------------------------------------
// Phase 1: partial[chunk][b][r] = sum_{d in chunk} xc[b][d] * V[d][r]
//   xc = x * (1 - mask) (complement path)
// ---------------------------------------------------------------------------
__global__ __launch_bounds__(512)
void lr_partial_kernel(const float* __restrict__ x,
                       const float* __restrict__ scale,
                       const float* __restrict__ thp,
                       const float* __restrict__ V,
                       float* __restrict__ partial)
{
    __shared__ float xc[NB * DCH];
    const int chunk = blockIdx.x;
    const int t = threadIdx.x;
    const float th = thp[0];
    if (t < NB * DCH) {
        const int b = t / DCH, dd = t % DCH;
        const int d = chunk * DCH + dd;
        const float xv = x[b * DIN + d];
        xc[t] = (fabsf(xv * scale[d]) > th) ? 0.f : xv;
    }
    __syncthreads();
    const int r = t; // 0..511
    float a0 = 0.f, a1 = 0.f, a2 = 0.f, a3 = 0.f;
    #pragma unroll
    for (int dd = 0; dd < DCH; ++dd) {
        const float v = V[(size_t)(chunk * DCH + dd) * RANK + r];
        a0 = fmaf(xc[0 * DCH + dd], v, a0);
        a1 = fmaf(xc[1 * DCH + dd], v, a1);
        a2 = fmaf(xc[2 * DCH + dd], v, a2);
        a3 = fmaf(xc[3 * DCH + dd], v, a3);
    }
    float* p = partial + (size_t)chunk * (NB * RANK) + r;
    p[0 * RANK] = a0;
    p[1 * RANK] = a1;
    p[2 * RANK] = a2;
    p[3 * RANK] = a3;
}

// ---------------------------------------------------------------------------
// Phase 2: lr[b][r] = S[r] * sum_chunk partial[chunk][b][r]
// ---------------------------------------------------------------------------
__global__ __launch_bounds__(64)
void lr_reduce_kernel(const float* __restrict__ partial,
                      const float* __restrict__ S,
                      float* __restrict__ lr)
{
    const int idx = blockIdx.x * 64 + threadIdx.x; // 0..NB*RANK-1
    const int r = idx & (RANK - 1);
    float s = 0.f;
    #pragma unroll 8
    for (int c = 0; c < NCHUNK; ++c)
        s += partial[(size_t)c * (NB * RANK) + idx];
    lr[idx] = s * S[r];
}

// ---------------------------------------------------------------------------
// Main: out[b][o] = bias[o] + sum_d xs[b][d]*W[o][d] + sum_r lr[b][r]*U[o][r]
// One wave per output row o (4 waves/block, no LDS -> high occupancy).
// W reads coalesced float4 (1 KB/wave/instr); xs/lr hit L1/L2.
// ---------------------------------------------------------------------------
__global__ __launch_bounds__(256)
void rsparse_main_kernel(const float* __restrict__ xs,
                         const float* __restrict__ W,
                         const float* __restrict__ bias,
                         const float* __restrict__ U,
                         const float* __restrict__ lr,
                         float* __restrict__ out)
{
    const int tid  = threadIdx.x;
    const int wave = tid >> 6, lane = tid & 63;
    const int o = blockIdx.x * 4 + wave;

    const float4* __restrict__ Wr = (const float4*)(W + (size_t)o * DIN);
    const float4* __restrict__ XS = (const float4*)xs; // [NB][1024]
    const float4* __restrict__ Ur = (const float4*)(U + (size_t)o * RANK);
    const float4* __restrict__ LR = (const float4*)lr; // [NB][128]

    float acc[NB] = {0.f, 0.f, 0.f, 0.f};

    #pragma unroll 4
    for (int k = 0; k < 16; ++k) {
        const int c = (k << 6) + lane;
        const float4 w = Wr[c];
        #pragma unroll
        for (int b = 0; b < NB; ++b) {
            const float4 xv = XS[b * 1024 + c];
            acc[b] = fmaf(w.x, xv.x, acc[b]);
            acc[b] = fmaf(w.y, xv.y, acc[b]);
            acc[b] = fmaf(w.z, xv.z, acc[b]);
            acc[b] = fmaf(w.w, xv.w, acc[b]);
        }
    }

    #pragma unroll
    for (int j = 0; j < 2; ++j) {
        const int c = (j << 6) + lane;
        const float4 u = Ur[c];
        #pragma unroll
        for (int b = 0; b < NB; ++b) {
            const float4 lv = LR[b * 128 + c];
            acc[b] = fmaf(u.x, lv.x, acc[b]);
            acc[b] = fmaf(u.y, lv.y, acc[b]);
            acc[b] = fmaf(u.z, lv.z, acc[b]);
            acc[b] = fmaf(u.w, lv.w, acc[b]);
        }
    }

    // 64-lane butterfly reduction
    #pragma unroll
    for (int b = 0; b < NB; ++b) {
        #pragma unroll
        for (int m = 32; m >= 1; m >>= 1)
            acc[b] += __shfl_xor(acc[b], m, 64);
    }

    if (lane == 0) {
        const float bi = bias[o];
        #pragma unroll
        for (int b = 0; b < NB; ++b)
            out[b * DOUT + o] = acc[b] + bi;
    }
}

// ---------------------------------------------------------------------------
extern "C" void kernel_launch(void* const* d_in, const int* in_sizes, int n_in,
                              void* d_out, int out_size, void* d_ws, size_t ws_size,
                              hipStream_t stream)
{
    const float* x     = (const float*)d_in[0]; // [4][1][4096]
    const float* W     = (const float*)d_in[1]; // [11008][4096]
    const float* bias  = (const float*)d_in[2]; // [11008]
    const float* U     = (const float*)d_in[3]; // [11008][512]
    const float* S     = (const float*)d_in[4]; // [512]
    const float* V     = (const float*)d_in[5]; // [4096][512]
    const float* scale = (const float*)d_in[6]; // [4096]
    const float* thp   = (const float*)d_in[7]; // [1]
    float* out = (float*)d_out;                 // [4][1][11008]

    float* partial = (float*)d_ws;                         // 2 MB
    float* lr      = partial + (size_t)NCHUNK * NB * RANK; // 8 KB
    float* xs      = lr + NB * RANK;                       // 64 KB

    prep_xs_kernel<<<(NB * DIN) / 256, 256, 0, stream>>>(x, scale, thp, xs);
    lr_partial_kernel<<<NCHUNK, 512, 0, stream>>>(x, scale, thp, V, partial);
    lr_reduce_kernel<<<(NB * RANK) / 64, 64, 0, stream>>>(partial, S, lr);

    rsparse_main_kernel<<<DOUT / 4, 256, 0, stream>>>(xs, W, bias, U, lr, out);
}

// Round 3
// 57.314 us; speedup vs baseline: 1.8991x; 1.1024x over previous
//
#include <hip/hip_runtime.h>
#include <cmath>

// Problem constants: B=4, T=1, DIN=4096, DOUT=11008, RANK=512
constexpr int DIN  = 4096;
constexpr int DOUT = 11008;
constexpr int RANK = 512;
constexpr int NB   = 4;

constexpr int NCHUNK = 256;          // d-chunks for lr partials
constexpr int DCH    = DIN / NCHUNK; // 16 d's per chunk

// ---------------------------------------------------------------------------
// Phase 1 (fused prep): for this chunk's 16 d's:
//   xs[b][d]  = x*mask   (written to workspace, consumed by main)
//   xc (LDS)  = x*(1-mask)
//   partial[chunk][b][r] = sum_{d in chunk} xc[b][d] * V[d][r]
// ---------------------------------------------------------------------------
__global__ __launch_bounds__(512)
void lr_partial_kernel(const float* __restrict__ x,
                       const float* __restrict__ scale,
                       const float* __restrict__ thp,
                       const float* __restrict__ V,
                       float* __restrict__ partial,
                       float* __restrict__ xs)
{
    __shared__ float xc[NB * DCH];
    const int chunk = blockIdx.x;
    const int t = threadIdx.x;
    const float th = thp[0];
    if (t < NB * DCH) {
        const int b = t / DCH, dd = t % DCH;
        const int d = chunk * DCH + dd;
        const float xv = x[b * DIN + d];
        const bool keep = fabsf(xv * scale[d]) > th; // mask==1 -> sparse path
        xc[t] = keep ? 0.f : xv;
        xs[b * DIN + d] = keep ? xv : 0.f;
    }
    __syncthreads();
    const int r = t; // 0..511
    float a0 = 0.f, a1 = 0.f, a2 = 0.f, a3 = 0.f;
    #pragma unroll
    for (int dd = 0; dd < DCH; ++dd) {
        const float v = V[(size_t)(chunk * DCH + dd) * RANK + r];
        a0 = fmaf(xc[0 * DCH + dd], v, a0);
        a1 = fmaf(xc[1 * DCH + dd], v, a1);
        a2 = fmaf(xc[2 * DCH + dd], v, a2);
        a3 = fmaf(xc[3 * DCH + dd], v, a3);
    }
    float* p = partial + (size_t)chunk * (NB * RANK) + r;
    p[0 * RANK] = a0;
    p[1 * RANK] = a1;
    p[2 * RANK] = a2;
    p[3 * RANK] = a3;
}

// ---------------------------------------------------------------------------
// Phase 2: lr[b][r] = S[r] * sum_chunk partial[chunk][b][r]
// ---------------------------------------------------------------------------
__global__ __launch_bounds__(64)
void lr_reduce_kernel(const float* __restrict__ partial,
                      const float* __restrict__ S,
                      float* __restrict__ lr)
{
    const int idx = blockIdx.x * 64 + threadIdx.x; // 0..NB*RANK-1
    const int r = idx & (RANK - 1);
    float s = 0.f;
    #pragma unroll 8
    for (int c = 0; c < NCHUNK; ++c)
        s += partial[(size_t)c * (NB * RANK) + idx];
    lr[idx] = s * S[r];
}

// ---------------------------------------------------------------------------
// Main: out[b][o] = bias[o] + sum_d xs[b][d]*W[o][d] + sum_r lr[b][r]*U[o][r]
// TWO output rows per wave: xs loads amortized over 2 W rows
// (per iter: 2 W float4 + 4 xs float4 -> 3 L1-bytes per W-byte, 32 FMAs).
// No LDS; 4 waves/block, 8 rows/block.
// ---------------------------------------------------------------------------
__global__ __launch_bounds__(256)
void rsparse_main_kernel(const float* __restrict__ xs,
                         const float* __restrict__ W,
                         const float* __restrict__ bias,
                         const float* __restrict__ U,
                         const float* __restrict__ lr,
                         float* __restrict__ out)
{
    const int tid  = threadIdx.x;
    const int wave = tid >> 6, lane = tid & 63;
    const int o0 = blockIdx.x * 8 + wave * 2;
    const int o1 = o0 + 1;

    const float4* __restrict__ W0 = (const float4*)(W + (size_t)o0 * DIN);
    const float4* __restrict__ W1 = (const float4*)(W + (size_t)o1 * DIN);
    const float4* __restrict__ XS = (const float4*)xs; // [NB][1024]
    const float4* __restrict__ U0 = (const float4*)(U + (size_t)o0 * RANK);
    const float4* __restrict__ U1 = (const float4*)(U + (size_t)o1 * RANK);
    const float4* __restrict__ LR = (const float4*)lr; // [NB][128]

    float acc0[NB] = {0.f, 0.f, 0.f, 0.f};
    float acc1[NB] = {0.f, 0.f, 0.f, 0.f};

    #pragma unroll 4
    for (int k = 0; k < 16; ++k) {
        const int c = (k << 6) + lane;
        const float4 w0 = W0[c];
        const float4 w1 = W1[c];
        #pragma unroll
        for (int b = 0; b < NB; ++b) {
            const float4 xv = XS[b * 1024 + c];
            acc0[b] = fmaf(w0.x, xv.x, acc0[b]);
            acc0[b] = fmaf(w0.y, xv.y, acc0[b]);
            acc0[b] = fmaf(w0.z, xv.z, acc0[b]);
            acc0[b] = fmaf(w0.w, xv.w, acc0[b]);
            acc1[b] = fmaf(w1.x, xv.x, acc1[b]);
            acc1[b] = fmaf(w1.y, xv.y, acc1[b]);
            acc1[b] = fmaf(w1.z, xv.z, acc1[b]);
            acc1[b] = fmaf(w1.w, xv.w, acc1[b]);
        }
    }

    #pragma unroll
    for (int j = 0; j < 2; ++j) {
        const int c = (j << 6) + lane;
        const float4 u0 = U0[c];
        const float4 u1 = U1[c];
        #pragma unroll
        for (int b = 0; b < NB; ++b) {
            const float4 lv = LR[b * 128 + c];
            acc0[b] = fmaf(u0.x, lv.x, acc0[b]);
            acc0[b] = fmaf(u0.y, lv.y, acc0[b]);
            acc0[b] = fmaf(u0.z, lv.z, acc0[b]);
            acc0[b] = fmaf(u0.w, lv.w, acc0[b]);
            acc1[b] = fmaf(u1.x, lv.x, acc1[b]);
            acc1[b] = fmaf(u1.y, lv.y, acc1[b]);
            acc1[b] = fmaf(u1.z, lv.z, acc1[b]);
            acc1[b] = fmaf(u1.w, lv.w, acc1[b]);
        }
    }

    // 64-lane butterfly reduction
    #pragma unroll
    for (int b = 0; b < NB; ++b) {
        #pragma unroll
        for (int m = 32; m >= 1; m >>= 1) {
            acc0[b] += __shfl_xor(acc0[b], m, 64);
            acc1[b] += __shfl_xor(acc1[b], m, 64);
        }
    }

    if (lane == 0) {
        const float bi0 = bias[o0], bi1 = bias[o1];
        #pragma unroll
        for (int b = 0; b < NB; ++b) {
            out[b * DOUT + o0] = acc0[b] + bi0;
            out[b * DOUT + o1] = acc1[b] + bi1;
        }
    }
}

// ---------------------------------------------------------------------------
extern "C" void kernel_launch(void* const* d_in, const int* in_sizes, int n_in,
                              void* d_out, int out_size, void* d_ws, size_t ws_size,
                              hipStream_t stream)
{
    const float* x     = (const float*)d_in[0]; // [4][1][4096]
    const float* W     = (const float*)d_in[1]; // [11008][4096]
    const float* bias  = (const float*)d_in[2]; // [11008]
    const float* U     = (const float*)d_in[3]; // [11008][512]
    const float* S     = (const float*)d_in[4]; // [512]
    const float* V     = (const float*)d_in[5]; // [4096][512]
    const float* scale = (const float*)d_in[6]; // [4096]
    const float* thp   = (const float*)d_in[7]; // [1]
    float* out = (float*)d_out;                 // [4][1][11008]

    float* partial = (float*)d_ws;                         // 2 MB
    float* lr      = partial + (size_t)NCHUNK * NB * RANK; // 8 KB
    float* xs      = lr + NB * RANK;                       // 64 KB

    lr_partial_kernel<<<NCHUNK, 512, 0, stream>>>(x, scale, thp, V, partial, xs);
    lr_reduce_kernel<<<(NB * RANK) / 64, 64, 0, stream>>>(partial, S, lr);
    rsparse_main_kernel<<<DOUT / 8, 256, 0, stream>>>(xs, W, bias, U, lr, out);
}

// Round 4
// 52.720 us; speedup vs baseline: 2.0647x; 1.0872x over previous
//
#include <hip/hip_runtime.h>
#include <cmath>

// Problem constants: B=4, T=1, DIN=4096, DOUT=11008, RANK=512
constexpr int DIN  = 4096;
constexpr int DOUT = 11008;
constexpr int RANK = 512;
constexpr int NB   = 4;

constexpr int NCHUNK = 256;          // d-chunks for lr partials
constexpr int DCH    = DIN / NCHUNK; // 16 d's per chunk
constexpr int SPLITK = 2;

// ---------------------------------------------------------------------------
// Phase 1 (fused prep): xs[b][d] = x*mask -> ws;  xc = x*(1-mask) -> LDS;
// partial[chunk][b][r] = sum_{d in chunk} xc[b][d] * V[d][r]
// ---------------------------------------------------------------------------
__global__ __launch_bounds__(512)
void lr_partial_kernel(const float* __restrict__ x,
                       const float* __restrict__ scale,
                       const float* __restrict__ thp,
                       const float* __restrict__ V,
                       float* __restrict__ partial,
                       float* __restrict__ xs)
{
    __shared__ float xc[NB * DCH];
    const int chunk = blockIdx.x;
    const int t = threadIdx.x;
    const float th = thp[0];
    if (t < NB * DCH) {
        const int b = t / DCH, dd = t % DCH;
        const int d = chunk * DCH + dd;
        const float xv = x[b * DIN + d];
        const bool keep = fabsf(xv * scale[d]) > th; // mask==1 -> sparse path
        xc[t] = keep ? 0.f : xv;
        xs[b * DIN + d] = keep ? xv : 0.f;
    }
    __syncthreads();
    const int r = t; // 0..511
    float a0 = 0.f, a1 = 0.f, a2 = 0.f, a3 = 0.f;
    #pragma unroll
    for (int dd = 0; dd < DCH; ++dd) {
        const float v = V[(size_t)(chunk * DCH + dd) * RANK + r];
        a0 = fmaf(xc[0 * DCH + dd], v, a0);
        a1 = fmaf(xc[1 * DCH + dd], v, a1);
        a2 = fmaf(xc[2 * DCH + dd], v, a2);
        a3 = fmaf(xc[3 * DCH + dd], v, a3);
    }
    float* p = partial + (size_t)chunk * (NB * RANK) + r;
    p[0 * RANK] = a0;
    p[1 * RANK] = a1;
    p[2 * RANK] = a2;
    p[3 * RANK] = a3;
}

// ---------------------------------------------------------------------------
// Phase 2: lr[b][r] = S[r] * sum_chunk partial[chunk][b][r]
// 16 threads per output -> all 16 loads in flight, one latency round.
// grid = (NB*RANK*16)/256 = 128 blocks
// ---------------------------------------------------------------------------
__global__ __launch_bounds__(256)
void lr_reduce_kernel(const float* __restrict__ partial,
                      const float* __restrict__ S,
                      float* __restrict__ lr)
{
    const int t = blockIdx.x * 256 + threadIdx.x;
    const int idx = t >> 4;  // output index 0..NB*RANK-1
    const int s = t & 15;    // chunk-subset
    float sum = 0.f;
    #pragma unroll
    for (int j = 0; j < 16; ++j)
        sum += partial[(size_t)(s * 16 + j) * (NB * RANK) + idx];
    #pragma unroll
    for (int m = 8; m >= 1; m >>= 1)
        sum += __shfl_xor(sum, m, 64);
    if (s == 0)
        lr[idx] = sum * S[idx & (RANK - 1)];
}

// ---------------------------------------------------------------------------
// Main (split-K=2): part[kh][b][o] = sum_{d in half kh} xs[b][d]*W[o][d]
//                    (+ U.lr term, added by kh==0 waves only)
// Wave -> (o-pair, k-half). Block = 4 waves = 2 o-pairs x 2 halves.
// 11008 waves total -> 8 waves/SIMD for max latency hiding; no LDS.
// ---------------------------------------------------------------------------
__global__ __launch_bounds__(256)
void rsparse_main_kernel(const float* __restrict__ xs,
                         const float* __restrict__ W,
                         const float* __restrict__ U,
                         const float* __restrict__ lr,
                         float* __restrict__ part)
{
    const int tid  = threadIdx.x;
    const int wave = tid >> 6, lane = tid & 63;
    const int pair = blockIdx.x * 2 + (wave >> 1);
    const int kh   = wave & 1;
    const int o0 = pair * 2, o1 = o0 + 1;
    const int kbase = kh * (DIN / SPLITK / 4); // float4 units: 0 or 512

    const float4* __restrict__ W0 = (const float4*)(W + (size_t)o0 * DIN);
    const float4* __restrict__ W1 = (const float4*)(W + (size_t)o1 * DIN);
    const float4* __restrict__ XS = (const float4*)xs; // [NB][1024]

    float acc0[NB] = {0.f, 0.f, 0.f, 0.f};
    float acc1[NB] = {0.f, 0.f, 0.f, 0.f};

    #pragma unroll 4
    for (int k = 0; k < 8; ++k) {
        const int c = kbase + (k << 6) + lane;
        const float4 w0 = W0[c];
        const float4 w1 = W1[c];
        #pragma unroll
        for (int b = 0; b < NB; ++b) {
            const float4 xv = XS[b * 1024 + c];
            acc0[b] = fmaf(w0.x, xv.x, acc0[b]);
            acc0[b] = fmaf(w0.y, xv.y, acc0[b]);
            acc0[b] = fmaf(w0.z, xv.z, acc0[b]);
            acc0[b] = fmaf(w0.w, xv.w, acc0[b]);
            acc1[b] = fmaf(w1.x, xv.x, acc1[b]);
            acc1[b] = fmaf(w1.y, xv.y, acc1[b]);
            acc1[b] = fmaf(w1.z, xv.z, acc1[b]);
            acc1[b] = fmaf(w1.w, xv.w, acc1[b]);
        }
    }

    if (kh == 0) { // U.lr term once per o-pair
        const float4* __restrict__ U0 = (const float4*)(U + (size_t)o0 * RANK);
        const float4* __restrict__ U1 = (const float4*)(U + (size_t)o1 * RANK);
        const float4* __restrict__ LR = (const float4*)lr; // [NB][128]
        #pragma unroll
        for (int j = 0; j < 2; ++j) {
            const int c = (j << 6) + lane;
            const float4 u0 = U0[c];
            const float4 u1 = U1[c];
            #pragma unroll
            for (int b = 0; b < NB; ++b) {
                const float4 lv = LR[b * 128 + c];
                acc0[b] = fmaf(u0.x, lv.x, acc0[b]);
                acc0[b] = fmaf(u0.y, lv.y, acc0[b]);
                acc0[b] = fmaf(u0.z, lv.z, acc0[b]);
                acc0[b] = fmaf(u0.w, lv.w, acc0[b]);
                acc1[b] = fmaf(u1.x, lv.x, acc1[b]);
                acc1[b] = fmaf(u1.y, lv.y, acc1[b]);
                acc1[b] = fmaf(u1.z, lv.z, acc1[b]);
                acc1[b] = fmaf(u1.w, lv.w, acc1[b]);
            }
        }
    }

    #pragma unroll
    for (int b = 0; b < NB; ++b) {
        #pragma unroll
        for (int m = 32; m >= 1; m >>= 1) {
            acc0[b] += __shfl_xor(acc0[b], m, 64);
            acc1[b] += __shfl_xor(acc1[b], m, 64);
        }
    }

    if (lane == 0) {
        float* p = part + (size_t)kh * (NB * DOUT);
        #pragma unroll
        for (int b = 0; b < NB; ++b) {
            p[b * DOUT + o0] = acc0[b];
            p[b * DOUT + o1] = acc1[b];
        }
    }
}

// ---------------------------------------------------------------------------
// Final: out[b][o] = part[0][b][o] + part[1][b][o] + bias[o]
// grid = NB*DOUT/256 = 172 blocks (exact)
// ---------------------------------------------------------------------------
__global__ __launch_bounds__(256)
void final_add_kernel(const float* __restrict__ part,
                      const float* __restrict__ bias,
                      float* __restrict__ out)
{
    const int i = blockIdx.x * 256 + threadIdx.x; // 0..NB*DOUT-1
    const int o = i % DOUT;
    out[i] = part[i] + part[NB * DOUT + i] + bias[o];
}

// ---------------------------------------------------------------------------
extern "C" void kernel_launch(void* const* d_in, const int* in_sizes, int n_in,
                              void* d_out, int out_size, void* d_ws, size_t ws_size,
                              hipStream_t stream)
{
    const float* x     = (const float*)d_in[0]; // [4][1][4096]
    const float* W     = (const float*)d_in[1]; // [11008][4096]
    const float* bias  = (const float*)d_in[2]; // [11008]
    const float* U     = (const float*)d_in[3]; // [11008][512]
    const float* S     = (const float*)d_in[4]; // [512]
    const float* V     = (const float*)d_in[5]; // [4096][512]
    const float* scale = (const float*)d_in[6]; // [4096]
    const float* thp   = (const float*)d_in[7]; // [1]
    float* out = (float*)d_out;                 // [4][1][11008]

    float* partial = (float*)d_ws;                          // 2 MB
    float* lr      = partial + (size_t)NCHUNK * NB * RANK;  // 8 KB
    float* xs      = lr + NB * RANK;                        // 64 KB
    float* part    = xs + NB * DIN;                         // 352 KB

    lr_partial_kernel<<<NCHUNK, 512, 0, stream>>>(x, scale, thp, V, partial, xs);
    lr_reduce_kernel<<<(NB * RANK * 16) / 256, 256, 0, stream>>>(partial, S, lr);
    rsparse_main_kernel<<<DOUT / 4, 256, 0, stream>>>(xs, W, U, lr, part);
    final_add_kernel<<<(NB * DOUT) / 256, 256, 0, stream>>>(part, bias, out);
}